// Round 3
// baseline (127.964 us; speedup 1.0000x reference)
//
#include <hip/hip_runtime.h>

#define B_ROWS 8192
#define FEAT   256
#define NCH    16          // j-range chunks -> grid = 16 x 64 = 1024 blocks (4/CU)
#define CH_COLS 512
#define NJT    8           // 64-col j-tiles per chunk

typedef float f32x4 __attribute__((ext_vector_type(4)));
typedef _Float16 f16x8 __attribute__((ext_vector_type(8)));

typedef const __attribute__((address_space(1))) unsigned int* gas_ptr;
typedef __attribute__((address_space(3))) unsigned int* las_ptr;

__device__ __forceinline__ void gload_lds16(const void* g, void* l) {
  // HW semantics: LDS dest = wave-uniform base + lane*16
  __builtin_amdgcn_global_load_lds((gas_ptr)g, (las_ptr)l, 16, 0, 0);
}

// ---- kernel 1: fp16 convert, row ssq, per-block f32 partials (R10, proven)
__global__ __launch_bounds__(256) void prep_kernel(
    const float* __restrict__ x, unsigned short* __restrict__ xh,
    float* __restrict__ sq, float* __restrict__ part_s,
    float* __restrict__ part_q)
{
  int tid = threadIdx.x;
  int l = tid & 63, wid = tid >> 6;
  int row = blockIdx.x * 4 + wid;
  const float4* xv = (const float4*)(x + (size_t)row * FEAT);
  float4 v = xv[l];
  ushort4 u;
  u.x = __builtin_bit_cast(unsigned short, (_Float16)v.x);
  u.y = __builtin_bit_cast(unsigned short, (_Float16)v.y);
  u.z = __builtin_bit_cast(unsigned short, (_Float16)v.z);
  u.w = __builtin_bit_cast(unsigned short, (_Float16)v.w);
  ((ushort4*)(xh + (size_t)row * FEAT))[l] = u;
  float ssq  = v.x*v.x + v.y*v.y + v.z*v.z + v.w*v.w;
  float ssum = v.x + v.y + v.z + v.w;
  #pragma unroll
  for (int m = 32; m; m >>= 1) {
    ssq  += __shfl_xor(ssq, m);
    ssum += __shfl_xor(ssum, m);
  }
  if (l == 0) sq[row] = ssq;
  __shared__ float red[8];
  if (l == 0) { red[wid*2] = ssum; red[wid*2+1] = ssq; }
  __syncthreads();
  if (tid == 0) {
    part_s[blockIdx.x] = red[0]+red[2]+red[4]+red[6];
    part_q[blockIdx.x] = red[1]+red[3]+red[5]+red[7];
  }
}

// ---- epilogue: wave tile 32(i) x 64(j), all waves share the 64-col j-tile
template<bool DIAG>
__device__ __forceinline__ void epilogue(
    const f32x4 (&acc)[2][4], const float* __restrict__ sq,
    const int* __restrict__ y, int j0, int l15,
    int i0q, const float (&sqi)[8], const int (&yiv)[8],
    float (&sden)[8], float (&snum)[8], float nscale2)
{
  int jb = j0 + l15;
  float sqj[4]; int yj[4];
  #pragma unroll
  for (int cb = 0; cb < 4; ++cb) {
    int j = jb + cb*16;
    sqj[cb] = sq[j];
    yj[cb]  = y[j];
  }
  #pragma unroll
  for (int rb = 0; rb < 2; ++rb) {
    #pragma unroll
    for (int r = 0; r < 4; ++r) {
      float si = sqi[rb*4+r];
      int   ig = i0q + rb*16 + r;
      int   yi = yiv[rb*4+r];
      float dacc = 0.f, nacc = 0.f;
      #pragma unroll
      for (int cb = 0; cb < 4; ++cb) {
        float S  = acc[rb][cb][r];
        float d2 = fmaf(S, -2.0f, si + sqj[cb]);
        d2 = fmaxf(d2, 0.0f);
        float e  = __builtin_amdgcn_exp2f(__builtin_amdgcn_sqrtf(d2) * nscale2);
        bool offd = !DIAG || (ig != jb + cb*16);
        dacc += offd ? e : 0.0f;
        nacc += (yi == yj[cb] && offd) ? e : 0.0f;
      }
      sden[rb*4+r] += dacc;
      snum[rb*4+r] += nacc;
    }
  }
}

// ---- kernel 2 (R10 inner structure, proven 60.5us @ 2 blocks/CU):
// block tile 128(i) x 64(j), 4 waves of 32x64. A fragments register-resident;
// LDS = single 32 KB B tile, static base, 2 barriers per j-tile.
// R13: occupancy lever only -- NCH 8->16 => 1024 blocks => 4 blocks/CU
// (VGPR ~116 <= 128 so HW schedules 4 waves/SIMD; 4 x 32 KB = 128 KB LDS ok).
// R11's launch_bounds(256,4) cap is NOT used: it forced VGPR=64 and spilled
// (FETCH 361 MB). R12's double-buffer/dynamic-base is reverted (+6us).
__global__ __launch_bounds__(256, 2) void snn_main(
    const unsigned short* __restrict__ xh, const float* __restrict__ sq,
    const int* __restrict__ y, const float* __restrict__ T,
    const float* __restrict__ part_s, const float* __restrict__ part_q,
    float* __restrict__ pden, float* __restrict__ pnum)
{
  __shared__ __align__(16) char lB[32768];
  int tid = threadIdx.x;
  int l = tid & 63, wid = tid >> 6;     // wid = wave row strip (0..3)
  int quad = l >> 4, l15 = l & 15;
  int l5 = l >> 5, s31 = l & 31;
  int ch = blockIdx.x, it = blockIdx.y;
  int i0 = it * 128, chbase = ch * CH_COLS;
  const char* xbc = (const char*)xh;

  // A fragments -> registers: lane holds A[m = wid*32+rb*16+l15]
  // [k = kk*32 + quad*8 .. +8] = 16 B at row*512 + kk*64 + quad*16
  f16x8 areg[2][8];
  #pragma unroll
  for (int rb = 0; rb < 2; ++rb)
    #pragma unroll
    for (int kk = 0; kk < 8; ++kk)
      areg[rb][kk] = *(const f16x8*)(xbc +
          (size_t)(i0 + wid*32 + rb*16 + l15)*512 + kk*64 + quad*16);

  // scale from prep's 2048 partials (per-wave redundant; no barrier)
  float s_acc = 0.f, q_acc = 0.f;
  #pragma unroll
  for (int t = 0; t < 32; ++t) {
    s_acc += part_s[l + 64*t];
    q_acc += part_q[l + 64*t];
  }
  #pragma unroll
  for (int m = 1; m <= 32; m <<= 1) {
    s_acc += __shfl_xor(s_acc, m);
    q_acc += __shfl_xor(q_acc, m);
  }
  const double n = (double)B_ROWS * FEAT;
  double var = ((double)q_acc - (double)s_acc*(double)s_acc/n) / (n - 1.0);
  float stdv = (float)sqrt(var);
  float p10  = __builtin_amdgcn_exp2f(T[0] * 3.3219280948873623f);
  float nscale2 = -(p10 * 1.4426950408889634f / stdv);

  // per-lane row stats
  float sqi[8]; int yiv[8];
  int i0q = i0 + wid*32 + quad*4;
  #pragma unroll
  for (int rb = 0; rb < 2; ++rb)
    #pragma unroll
    for (int r = 0; r < 4; ++r) {
      int idx = i0q + rb*16 + r;
      sqi[rb*4+r] = sq[idx];
      yiv[rb*4+r] = y[idx];
    }

  float sden[8], snum[8];
  #pragma unroll
  for (int v = 0; v < 8; ++v) { sden[v] = 0.f; snum[v] = 0.f; }
  f32x4 acc[2][4];
  const f32x4 zero4 = {0.f, 0.f, 0.f, 0.f};

  for (int jt = 0; jt < NJT; ++jt) {
    int j0 = chbase + jt * 64;

    __syncthreads();   // all waves done reading lB of previous tile
    // stage next B tile (64 cols x 512 B = 32 chunks of 1024 B) to LDS
    {
      const char* gB = xbc + (size_t)j0 * 512;
      #pragma unroll
      for (int s = 0; s < 8; ++s) {
        int c  = wid*8 + s;
        int rw = 2*c + l5;
        int gg = s31 ^ (rw & 7);
        gload_lds16(gB + rw*512 + gg*16, lB + c*1024);
      }
    }

    if (jt > 0) {
      int pj0 = j0 - 64;
      if (pj0 == i0 || pj0 == i0 + 64)
        epilogue<true >(acc, sq, y, pj0, l15, i0q, sqi, yiv, sden, snum, nscale2);
      else
        epilogue<false>(acc, sq, y, pj0, l15, i0q, sqi, yiv, sden, snum, nscale2);
    }
    #pragma unroll
    for (int rb = 0; rb < 2; ++rb)
      #pragma unroll
      for (int cb = 0; cb < 4; ++cb)
        acc[rb][cb] = zero4;

    __syncthreads();   // drains vmcnt: B tile visible

    #pragma unroll
    for (int kk = 0; kk < 8; ++kk) {
      f16x8 bv[4];
      #pragma unroll
      for (int cb = 0; cb < 4; ++cb) {
        int nr = cb*16 + l15;
        bv[cb] = *(const f16x8*)(lB + nr*512 + ((((kk<<2)|quad) ^ (l15 & 7)) << 4));
      }
      #pragma unroll
      for (int rb = 0; rb < 2; ++rb)
        #pragma unroll
        for (int cb = 0; cb < 4; ++cb)
          acc[rb][cb] = __builtin_amdgcn_mfma_f32_16x16x32_f16(areg[rb][kk], bv[cb], acc[rb][cb], 0, 0, 0);
    }
  }
  {
    int pj0 = chbase + (NJT-1) * 64;
    if (pj0 == i0 || pj0 == i0 + 64)
      epilogue<true >(acc, sq, y, pj0, l15, i0q, sqi, yiv, sden, snum, nscale2);
    else
      epilogue<false>(acc, sq, y, pj0, l15, i0q, sqi, yiv, sden, snum, nscale2);
  }

  // reduce across the 16 lanes of each quad (columns), store partials
  #pragma unroll
  for (int v = 0; v < 8; ++v) {
    #pragma unroll
    for (int m = 1; m <= 8; m <<= 1) {
      sden[v] += __shfl_xor(sden[v], m);
      snum[v] += __shfl_xor(snum[v], m);
    }
  }
  if (l15 == 0) {
    int base = (it*NCH + ch) * 128;
    #pragma unroll
    for (int rb = 0; rb < 2; ++rb)
      #pragma unroll
      for (int r = 0; r < 4; ++r) {
        int rin = wid*32 + rb*16 + quad*4 + r;
        pden[base + rin] = sden[rb*4+r];
        pnum[base + rin] = snum[rb*4+r];
      }
  }
}

// ---- kernel 3: single 1024-thread block; direct write (no memset/atomic).
// __builtin_amdgcn_logf is LOG2 -> scale by ln(2)  (R4/5/7/9 bug).
__global__ __launch_bounds__(1024) void final_kernel(
    const float* __restrict__ pden, const float* __restrict__ pnum,
    float* __restrict__ out)
{
  int tid = threadIdx.x;
  float tot = 0.f;
  #pragma unroll
  for (int rr = 0; rr < 8; ++rr) {
    int row = tid + 1024*rr;
    int itt = row >> 7, rin = row & 127;
    float den = 0.f, num = 0.f;
    #pragma unroll
    for (int p = 0; p < NCH; ++p) {
      den += pden[(itt*NCH + p)*128 + rin];
      num += pnum[(itt*NCH + p)*128 + rin];
    }
    if (num > 0.f)
      tot += 0.6931471805599453f *
             (__builtin_amdgcn_logf(num) - __builtin_amdgcn_logf(den));
  }
  #pragma unroll
  for (int m = 32; m; m >>= 1) tot += __shfl_xor(tot, m);
  __shared__ float red[16];
  if ((tid & 63) == 0) red[tid >> 6] = tot;
  __syncthreads();
  if (tid == 0) {
    float s = 0.f;
    #pragma unroll
    for (int w = 0; w < 16; ++w) s += red[w];
    out[0] = -s / 8192.0f;
  }
}

extern "C" void kernel_launch(void* const* d_in, const int* in_sizes, int n_in,
                              void* d_out, int out_size, void* d_ws, size_t ws_size,
                              hipStream_t stream)
{
  (void)in_sizes; (void)n_in; (void)out_size; (void)ws_size;
  const float* x  = (const float*)d_in[0];
  const int* y    = (const int*)d_in[1];   // int64 in reference -> int32 here (jax x64 off)
  const float* T  = (const float*)d_in[2];
  char* ws = (char*)d_ws;
  float* part_s = (float*)(ws + 1024);                   // 8 KB
  float* part_q = (float*)(ws + 1024 + 8192);            // 8 KB
  float* sq     = (float*)(ws + 32768);                  // 32 KB
  unsigned short* xh = (unsigned short*)(ws + 65536);    // 4 MB fp16
  float* pden   = (float*)(ws + 65536 + 4194304);        // 64*NCH*128 f32
  float* pnum   = pden + 64*NCH*128;

  hipLaunchKernelGGL(prep_kernel, dim3(B_ROWS/4), dim3(256), 0, stream,
                     x, xh, sq, part_s, part_q);
  hipLaunchKernelGGL(snn_main, dim3(NCH, B_ROWS/128), dim3(256), 0, stream,
                     xh, sq, y, T, part_s, part_q, pden, pnum);
  hipLaunchKernelGGL(final_kernel, dim3(1), dim3(1024), 0, stream,
                     pden, pnum, (float*)d_out);
}

// Round 4
// 121.610 us; speedup vs baseline: 1.0523x; 1.0523x over previous
//
#include <hip/hip_runtime.h>

#define B_ROWS 8192
#define FEAT   256
#define NCCH   8           // j-tile residue classes -> grid = 8 x 64 = 512 blocks
#define NJTILE 128         // total 64-col j-tiles

typedef float f32x4 __attribute__((ext_vector_type(4)));
typedef _Float16 f16x8 __attribute__((ext_vector_type(8)));

typedef const __attribute__((address_space(1))) unsigned int* gas_ptr;
typedef __attribute__((address_space(3))) unsigned int* las_ptr;

__device__ __forceinline__ void gload_lds16(const void* g, void* l) {
  // HW semantics: LDS dest = wave-uniform base + lane*16
  __builtin_amdgcn_global_load_lds((gas_ptr)g, (las_ptr)l, 16, 0, 0);
}

// ---- kernel 1: fp16 convert, row ssq, per-block f32 partials (R10, proven)
// R14: also zeroes col_den/col_num (atomic accumulators for the symmetric half)
__global__ __launch_bounds__(256) void prep_kernel(
    const float* __restrict__ x, unsigned short* __restrict__ xh,
    float* __restrict__ sq, float* __restrict__ part_s,
    float* __restrict__ part_q, float* __restrict__ col_den,
    float* __restrict__ col_num)
{
  int tid = threadIdx.x;
  int l = tid & 63, wid = tid >> 6;
  int row = blockIdx.x * 4 + wid;
  const float4* xv = (const float4*)(x + (size_t)row * FEAT);
  float4 v = xv[l];
  ushort4 u;
  u.x = __builtin_bit_cast(unsigned short, (_Float16)v.x);
  u.y = __builtin_bit_cast(unsigned short, (_Float16)v.y);
  u.z = __builtin_bit_cast(unsigned short, (_Float16)v.z);
  u.w = __builtin_bit_cast(unsigned short, (_Float16)v.w);
  ((ushort4*)(xh + (size_t)row * FEAT))[l] = u;
  if (tid < 4) {
    int r4 = blockIdx.x * 4 + tid;
    col_den[r4] = 0.f;
    col_num[r4] = 0.f;
  }
  float ssq  = v.x*v.x + v.y*v.y + v.z*v.z + v.w*v.w;
  float ssum = v.x + v.y + v.z + v.w;
  #pragma unroll
  for (int m = 32; m; m >>= 1) {
    ssq  += __shfl_xor(ssq, m);
    ssum += __shfl_xor(ssum, m);
  }
  if (l == 0) sq[row] = ssq;
  __shared__ float red[8];
  if (l == 0) { red[wid*2] = ssum; red[wid*2+1] = ssq; }
  __syncthreads();
  if (tid == 0) {
    part_s[blockIdx.x] = red[0]+red[2]+red[4]+red[6];
    part_q[blockIdx.x] = red[1]+red[3]+red[5]+red[7];
  }
}

// ---- epilogue: wave tile 32(i) x 64(j).
// DIAG: band tile (mask i==j), row-sums only.
// COL : far tile -- also col-sums (symmetric credit to rows j) via quad
//       shuffle-reduce + one masked atomicAdd per (cb,array).
template<bool DIAG, bool COL>
__device__ __forceinline__ void epilogue(
    const f32x4 (&acc)[2][4], const float* __restrict__ sq,
    const int* __restrict__ y, int j0, int l15, int l,
    int i0q, const float (&sqi)[8], const int (&yiv)[8],
    float (&sden)[8], float (&snum)[8], float nscale2,
    float* __restrict__ col_den, float* __restrict__ col_num)
{
  int jb = j0 + l15;
  float sqj[4]; int yj[4];
  #pragma unroll
  for (int cb = 0; cb < 4; ++cb) {
    int j = jb + cb*16;
    sqj[cb] = sq[j];
    yj[cb]  = y[j];
  }
  float cd[4], cn[4];
  if (COL) {
    #pragma unroll
    for (int cb = 0; cb < 4; ++cb) { cd[cb] = 0.f; cn[cb] = 0.f; }
  }
  #pragma unroll
  for (int rb = 0; rb < 2; ++rb) {
    #pragma unroll
    for (int r = 0; r < 4; ++r) {
      float si = sqi[rb*4+r];
      int   ig = i0q + rb*16 + r;
      int   yi = yiv[rb*4+r];
      float dacc = 0.f, nacc = 0.f;
      #pragma unroll
      for (int cb = 0; cb < 4; ++cb) {
        float S  = acc[rb][cb][r];
        float d2 = fmaf(S, -2.0f, si + sqj[cb]);
        d2 = fmaxf(d2, 0.0f);
        float e  = __builtin_amdgcn_exp2f(__builtin_amdgcn_sqrtf(d2) * nscale2);
        bool same = (yi == yj[cb]);
        bool offd = !DIAG || (ig != jb + cb*16);
        dacc += offd ? e : 0.0f;
        nacc += (same && offd) ? e : 0.0f;
        if (COL) {
          cd[cb] += e;
          cn[cb] += same ? e : 0.0f;
        }
      }
      sden[rb*4+r] += dacc;
      snum[rb*4+r] += nacc;
    }
  }
  if (COL) {
    #pragma unroll
    for (int cb = 0; cb < 4; ++cb) {
      cd[cb] += __shfl_xor(cd[cb], 16);
      cd[cb] += __shfl_xor(cd[cb], 32);
      cn[cb] += __shfl_xor(cn[cb], 16);
      cn[cb] += __shfl_xor(cn[cb], 32);
    }
    if (l < 16) {
      #pragma unroll
      for (int cb = 0; cb < 4; ++cb) {
        atomicAdd(&col_den[j0 + cb*16 + l], cd[cb]);
        atomicAdd(&col_num[j0 + cb*16 + l], cn[cb]);
      }
    }
  }
}

// ---- kernel 2 (R14: triangular): block tile 128(i) x 64(j), 4 waves of
// 32x64, R10 inner structure (static 32 KB LDS, 2 barriers/tile, A in regs).
// Symmetry: only j-tiles jt >= 2*it are computed (4160 of 8192 tiles).
//   band tiles (jt>>1 == it): full compute, DIAG mask, row-sums only
//   far tiles  (jt >= 2it+2): row-sums AND col-sums (credit rows j via
//     atomicAdd into col_den/col_num -- e(i,j)=e(j,i))
// Block (c, yb): it = yb<32 ? yb : 95-yb  (pairs it with 63-it in dispatch
// order so each CU's two blocks sum to ~130/8 tiles -- balanced makespan).
// j-tiles: jt ≡ c (mod 8), jt >= 2it.
__global__ __launch_bounds__(256, 2) void snn_main(
    const unsigned short* __restrict__ xh, const float* __restrict__ sq,
    const int* __restrict__ y, const float* __restrict__ T,
    const float* __restrict__ part_s, const float* __restrict__ part_q,
    float* __restrict__ pden, float* __restrict__ pnum,
    float* __restrict__ col_den, float* __restrict__ col_num)
{
  __shared__ __align__(16) char lB[32768];
  int tid = threadIdx.x;
  int l = tid & 63, wid = tid >> 6;     // wid = wave row strip (0..3)
  int quad = l >> 4, l15 = l & 15;
  int l5 = l >> 5, s31 = l & 31;
  int c = blockIdx.x, yb = blockIdx.y;
  int it = (yb < 32) ? yb : 95 - yb;    // complementary pairing
  int i0 = it * 128;
  const char* xbc = (const char*)xh;

  // A fragments -> registers: lane holds A[m = wid*32+rb*16+l15]
  // [k = kk*32 + quad*8 .. +8] = 16 B at row*512 + kk*64 + quad*16
  f16x8 areg[2][8];
  #pragma unroll
  for (int rb = 0; rb < 2; ++rb)
    #pragma unroll
    for (int kk = 0; kk < 8; ++kk)
      areg[rb][kk] = *(const f16x8*)(xbc +
          (size_t)(i0 + wid*32 + rb*16 + l15)*512 + kk*64 + quad*16);

  // scale from prep's 2048 partials (per-wave redundant; no barrier)
  float s_acc = 0.f, q_acc = 0.f;
  #pragma unroll
  for (int t = 0; t < 32; ++t) {
    s_acc += part_s[l + 64*t];
    q_acc += part_q[l + 64*t];
  }
  #pragma unroll
  for (int m = 1; m <= 32; m <<= 1) {
    s_acc += __shfl_xor(s_acc, m);
    q_acc += __shfl_xor(q_acc, m);
  }
  const double n = (double)B_ROWS * FEAT;
  double var = ((double)q_acc - (double)s_acc*(double)s_acc/n) / (n - 1.0);
  float stdv = (float)sqrt(var);
  float p10  = __builtin_amdgcn_exp2f(T[0] * 3.3219280948873623f);
  float nscale2 = -(p10 * 1.4426950408889634f / stdv);

  // per-lane row stats
  float sqi[8]; int yiv[8];
  int i0q = i0 + wid*32 + quad*4;
  #pragma unroll
  for (int rb = 0; rb < 2; ++rb)
    #pragma unroll
    for (int r = 0; r < 4; ++r) {
      int idx = i0q + rb*16 + r;
      sqi[rb*4+r] = sq[idx];
      yiv[rb*4+r] = y[idx];
    }

  float sden[8], snum[8];
  #pragma unroll
  for (int v = 0; v < 8; ++v) { sden[v] = 0.f; snum[v] = 0.f; }
  f32x4 acc[2][4];
  const f32x4 zero4 = {0.f, 0.f, 0.f, 0.f};

  // first j-tile: smallest jt >= 2it with jt ≡ c (mod 8)
  int f = 2*it + ((c - 2*it) & 7);
  int pjt = -1;

  for (int jt = f; jt < NJTILE; jt += 8) {
    int j0 = jt * 64;

    __syncthreads();   // all waves done reading lB of previous tile
    // stage B tile jt (64 cols x 512 B = 32 chunks of 1024 B) to LDS
    {
      const char* gB = xbc + (size_t)j0 * 512;
      #pragma unroll
      for (int s = 0; s < 8; ++s) {
        int cc = wid*8 + s;
        int rw = 2*cc + l5;
        int gg = s31 ^ (rw & 7);
        gload_lds16(gB + rw*512 + gg*16, lB + cc*1024);
      }
    }

    if (pjt >= 0) {
      int pj0 = pjt * 64;
      if ((pjt >> 1) == it)
        epilogue<true , false>(acc, sq, y, pj0, l15, l, i0q, sqi, yiv,
                               sden, snum, nscale2, col_den, col_num);
      else
        epilogue<false, true >(acc, sq, y, pj0, l15, l, i0q, sqi, yiv,
                               sden, snum, nscale2, col_den, col_num);
    }
    #pragma unroll
    for (int rb = 0; rb < 2; ++rb)
      #pragma unroll
      for (int cb = 0; cb < 4; ++cb)
        acc[rb][cb] = zero4;

    __syncthreads();   // drains vmcnt: B tile visible

    #pragma unroll
    for (int kk = 0; kk < 8; ++kk) {
      f16x8 bv[4];
      #pragma unroll
      for (int cb = 0; cb < 4; ++cb) {
        int nr = cb*16 + l15;
        bv[cb] = *(const f16x8*)(lB + nr*512 + ((((kk<<2)|quad) ^ (l15 & 7)) << 4));
      }
      #pragma unroll
      for (int rb = 0; rb < 2; ++rb)
        #pragma unroll
        for (int cb = 0; cb < 4; ++cb)
          acc[rb][cb] = __builtin_amdgcn_mfma_f32_16x16x32_f16(areg[rb][kk], bv[cb], acc[rb][cb], 0, 0, 0);
    }
    pjt = jt;
  }
  if (pjt >= 0) {
    int pj0 = pjt * 64;
    if ((pjt >> 1) == it)
      epilogue<true , false>(acc, sq, y, pj0, l15, l, i0q, sqi, yiv,
                             sden, snum, nscale2, col_den, col_num);
    else
      epilogue<false, true >(acc, sq, y, pj0, l15, l, i0q, sqi, yiv,
                             sden, snum, nscale2, col_den, col_num);
  }

  // reduce row-sums across the 16 lanes of each quad, store partials
  #pragma unroll
  for (int v = 0; v < 8; ++v) {
    #pragma unroll
    for (int m = 1; m <= 8; m <<= 1) {
      sden[v] += __shfl_xor(sden[v], m);
      snum[v] += __shfl_xor(snum[v], m);
    }
  }
  if (l15 == 0) {
    int base = (it*NCCH + c) * 128;
    #pragma unroll
    for (int rb = 0; rb < 2; ++rb)
      #pragma unroll
      for (int r = 0; r < 4; ++r) {
        int rin = wid*32 + rb*16 + quad*4 + r;
        pden[base + rin] = sden[rb*4+r];
        pnum[base + rin] = snum[rb*4+r];
      }
  }
}

// ---- kernel 3: single 1024-thread block; direct write (no memset/atomic).
// __builtin_amdgcn_logf is LOG2 -> scale by ln(2)  (R4/5/7/9 bug).
// R14: den/num = 8 row-chunk partials + symmetric col accumulators.
__global__ __launch_bounds__(1024) void final_kernel(
    const float* __restrict__ pden, const float* __restrict__ pnum,
    const float* __restrict__ col_den, const float* __restrict__ col_num,
    float* __restrict__ out)
{
  int tid = threadIdx.x;
  float tot = 0.f;
  #pragma unroll
  for (int rr = 0; rr < 8; ++rr) {
    int row = tid + 1024*rr;
    int itt = row >> 7, rin = row & 127;
    float den = col_den[row], num = col_num[row];
    #pragma unroll
    for (int p = 0; p < NCCH; ++p) {
      den += pden[(itt*NCCH + p)*128 + rin];
      num += pnum[(itt*NCCH + p)*128 + rin];
    }
    if (num > 0.f)
      tot += 0.6931471805599453f *
             (__builtin_amdgcn_logf(num) - __builtin_amdgcn_logf(den));
  }
  #pragma unroll
  for (int m = 32; m; m >>= 1) tot += __shfl_xor(tot, m);
  __shared__ float red[16];
  if ((tid & 63) == 0) red[tid >> 6] = tot;
  __syncthreads();
  if (tid == 0) {
    float s = 0.f;
    #pragma unroll
    for (int w = 0; w < 16; ++w) s += red[w];
    out[0] = -s / 8192.0f;
  }
}

extern "C" void kernel_launch(void* const* d_in, const int* in_sizes, int n_in,
                              void* d_out, int out_size, void* d_ws, size_t ws_size,
                              hipStream_t stream)
{
  (void)in_sizes; (void)n_in; (void)out_size; (void)ws_size;
  const float* x  = (const float*)d_in[0];
  const int* y    = (const int*)d_in[1];   // int64 in reference -> int32 here (jax x64 off)
  const float* T  = (const float*)d_in[2];
  char* ws = (char*)d_ws;
  float* part_s = (float*)(ws + 1024);                   // 8 KB
  float* part_q = (float*)(ws + 1024 + 8192);            // 8 KB
  float* sq     = (float*)(ws + 32768);                  // 32 KB
  unsigned short* xh = (unsigned short*)(ws + 65536);    // 4 MB fp16
  float* pden   = (float*)(ws + 65536 + 4194304);        // 64*8*128 f32 = 256 KB
  float* pnum   = pden + 64*NCCH*128;                    // 256 KB
  float* col_den = pnum + 64*NCCH*128;                   // 32 KB
  float* col_num = col_den + B_ROWS;                     // 32 KB

  hipLaunchKernelGGL(prep_kernel, dim3(B_ROWS/4), dim3(256), 0, stream,
                     x, xh, sq, part_s, part_q, col_den, col_num);
  hipLaunchKernelGGL(snn_main, dim3(NCCH, B_ROWS/128), dim3(256), 0, stream,
                     xh, sq, y, T, part_s, part_q, pden, pnum, col_den, col_num);
  hipLaunchKernelGGL(final_kernel, dim3(1), dim3(1024), 0, stream,
                     pden, pnum, col_den, col_num, (float*)d_out);
}